// Round 13
// baseline (72.985 us; speedup 1.0000x reference)
//
#include <hip/hip_runtime.h>
#include <math.h>
#include <stdint.h>

// Problem dims
#define NB  8
#define NC  256
#define NHW 4096   // H*W
#define NK  512

// d_out float offsets (outputs concatenated in return order)
#define OFF_SEL 0ULL
#define OFF_CW  8388608ULL              // NB*NC*NHW
#define OFF_KLD 8421376ULL              // + NB*NHW
#define OFF_MAT 8421377ULL              // + 1
#define MAT_COUNT 16777216ULL           // NB*NK*NHW
#define OUT_TOTAL (OFF_MAT + MAT_COUNT) // 25198593

typedef float f4v __attribute__((ext_vector_type(4)));

// ws layout: double sw[512]; double kld_accum; double ticket_slot;  (4112 bytes)

// DPP helpers: xor1=0xB1, xor2=0x4E, xor7(row_half_mirror)=0x141, xor15(row_mirror)=0x140
template <int C>
__device__ __forceinline__ float fdpp(float x) {
    return __int_as_float(__builtin_amdgcn_update_dpp(0, __float_as_int(x), C, 0xF, 0xF, true));
}
template <int C>
__device__ __forceinline__ int idpp(int x) {
    return __builtin_amdgcn_update_dpp(0, x, C, 0xF, 0xF, true);
}
__device__ __forceinline__ float fswz16(float x) {   // lane ^ 16
    return __int_as_float(__builtin_amdgcn_ds_swizzle(__float_as_int(x), 0x401F));
}
__device__ __forceinline__ int iswz16(int x) {
    return __builtin_amdgcn_ds_swizzle(x, 0x401F);
}

// Fused: zero-fill mat region (all 2048 blocks, NT float4 stream) + codebook
// channel-sum prep (blocks 0..127) + ws accumulator/ticket zeroing (block 0).
__global__ void zprep(const float* __restrict__ cb, double* __restrict__ ws,
                      float* __restrict__ out) {
    const size_t base4 = 2105345ULL;            // 8421380/4 : first 16B-aligned float4
    const size_t n4    = 4194303ULL;
    size_t i = (size_t)blockIdx.x * blockDim.x + threadIdx.x;
    const size_t stride = (size_t)gridDim.x * blockDim.x;
    f4v* o4 = reinterpret_cast<f4v*>(out) + base4;
    const f4v z = {0.f, 0.f, 0.f, 0.f};
    for (; i < n4; i += stride) __builtin_nontemporal_store(z, o4 + i);
    if (blockIdx.x == 0 && threadIdx.x < 4) {
        out[OFF_MAT + threadIdx.x] = 0.f;       // head floats
        if (threadIdx.x == 0) {
            out[OUT_TOTAL - 1] = 0.f;           // tail float
            ws[NK] = 0.0;                       // kld accumulator
            reinterpret_cast<unsigned*>(ws + NK + 1)[0] = 0u;   // ticket
        }
    }
    if (blockIdx.x < 128) {                     // codebook prep (r12-proven)
        const int l = threadIdx.x & 63;
        const int w = threadIdx.x >> 6;
        const int k = blockIdx.x * 4 + w;
        const float4 v = *reinterpret_cast<const float4*>(cb + (size_t)k * NC + l * 4);
        double s = (double)v.x + (double)v.y + (double)v.z + (double)v.w;
        #pragma unroll
        for (int off = 32; off > 0; off >>= 1) s += __shfl_xor(s, off);
        if (l == 0) ws[k] = s;
    }
}

// Wave-per-token, DPP reduce, depth-2 float4 prefetch, sparse mat scatter,
// last-block kld finalize. 512 threads, grid 512. LDS ~20.5 KB.
__global__ void __launch_bounds__(512, 4)
gs_main(const float* __restrict__ feats, const float* __restrict__ gumbel,
        const float* __restrict__ cb, double* __restrict__ ws,
        float* __restrict__ out) {
    __shared__ double part[8][64];
    __shared__ __align__(16) float sw_f[NK];
    __shared__ double sf_d[64];
    __shared__ float  sf_f[64];
    __shared__ int    kcnt[64];
    __shared__ int    klist[64][25];
    __shared__ float  wlist[64][25];
    __shared__ double kldp[8];

    const int tid = threadIdx.x;
    const int l   = tid & 63;
    const int w   = tid >> 6;
    const int b   = blockIdx.x >> 6;
    const int n0  = (blockIdx.x & 63) * 64;

    // ---- Phase A: sf[tok] = channel sum (f64); sw -> LDS f32 ----
    {
        const float* fp = feats + ((size_t)b * NC + w * 32) * NHW + n0 + l;
        double s = 0.0;
        #pragma unroll
        for (int i = 0; i < 32; ++i) s += (double)fp[(size_t)i * NHW];
        part[w][l] = s;
        sw_f[tid] = (float)ws[tid];
        __syncthreads();
        if (tid < 64) {
            double a = 0.0;
            #pragma unroll
            for (int i = 0; i < 8; ++i) a += part[i][tid];
            sf_d[tid] = a; sf_f[tid] = (float)a;
            kcnt[tid] = 0;
        }
        __syncthreads();
    }

    // lane's 8 sw values as two float4 (k = 4l+q and 256+4l+q)
    const float4 sa = *reinterpret_cast<const float4*>(&sw_f[4 * l]);
    const float4 sb = *reinterpret_cast<const float4*>(&sw_f[256 + 4 * l]);

    double kld_wave = 0.0;
    const float4* g4 = reinterpret_cast<const float4*>(
        gumbel + ((size_t)(b * NHW) + n0 + w * 8) * NK);   // 128 float4 per token row

    float4 A0 = g4[l],           A1 = g4[64 + l];          // token 0
    float4 B0 = g4[128 + l],     B1 = g4[192 + l];         // token 1
    float4 C0, C1;

#define KSTEP(kk, SV, GV) { \
        const float d_ = sft - (SV); \
        const float logit_ = __expf(-d_ * d_); \
        const float yy_ = logit_ + (GV); \
        y[kk] = yy_; \
        const float h_ = fmaf(logit_, fmaf(logit_, fmaf(logit_, fmaf(logit_, \
                          1.f/120.f, 1.f/24.f), 1.f/6.f), 0.5f), 1.f); \
        const float xh_ = logit_ * h_; \
        E += xh_; \
        T = fmaf(logit_, 1.f + xh_, T); \
        if (yy_ > M) { YS = M; M = yy_; KB = (kk < 4) ? (4*l + kk) : (256 + 4*l + kk - 4); } \
        else YS = fmaxf(YS, yy_); }

#define BSTEP(GF, GI) { \
        const float oM = GF(M); const int oK = GI(KB); \
        const float oY = GF(YS); const float oE = GF(E); const float oT = GF(T); \
        const float nys = fmaxf(fmaxf(YS, oY), fminf(M, oM)); \
        if (oM > M || (oM == M && oK < KB)) { M = oM; KB = oK; } \
        YS = nys; E += oE; T += oT; }

#define SH32(x) __shfl_xor(x, 32)

#define TOKEN(ii, CUR0, CUR1, PF) { \
        PF; \
        const int tt = w * 8 + ii; \
        const int n  = n0 + tt; \
        const float sft = sf_f[tt]; \
        float y[8]; \
        float M = -1.0e30f, YS = -1.0e30f; int KB = 0; \
        float E = 0.f, T = 0.f; \
        KSTEP(0, sa.x, (CUR0).x)  KSTEP(1, sa.y, (CUR0).y) \
        KSTEP(2, sa.z, (CUR0).z)  KSTEP(3, sa.w, (CUR0).w) \
        KSTEP(4, sb.x, (CUR1).x)  KSTEP(5, sb.y, (CUR1).y) \
        KSTEP(6, sb.z, (CUR1).z)  KSTEP(7, sb.w, (CUR1).w) \
        BSTEP(fdpp<0xB1>,  idpp<0xB1>) \
        BSTEP(fdpp<0x4E>,  idpp<0x4E>) \
        BSTEP(fdpp<0x141>, idpp<0x141>) \
        BSTEP(fdpp<0x140>, idpp<0x140>) \
        BSTEP(fswz16,      iswz16) \
        BSTEP(SH32,        SH32) \
        E += 512.f; \
        if (M - YS < 5e-3f) {               /* rare exact f64 argmax (wave-uniform) */ \
            const double sfd = sf_d[tt]; \
            const float* gsc = gumbel + ((size_t)(b * NHW) + n) * NK; \
            double ym64 = -1.0e300; int kb64 = 0; \
            _Pragma("unroll") \
            for (int jj = 0; jj < 8; ++jj) { \
                const int k_ = (jj < 4) ? (4*l + jj) : (256 + 4*l + jj - 4); \
                const double dd = sfd - ws[k_]; \
                const double aff = dd * dd; \
                const double lg = (aff < 45.0) ? exp(-aff) : 0.0; \
                const double yy = lg + (double)gsc[k_]; \
                if (yy > ym64) { ym64 = yy; kb64 = k_; } \
            } \
            _Pragma("unroll") \
            for (int off = 1; off < 64; off <<= 1) { \
                const double oy = __shfl_xor(ym64, off); \
                const int    ok = __shfl_xor(kb64, off); \
                if (oy > ym64 || (oy == ym64 && ok < kb64)) { ym64 = oy; kb64 = ok; } \
            } \
            KB = kb64; \
        } \
        if (l == 0) { \
            out[OFF_CW + (size_t)b * NHW + n] = (float)KB; \
            kld_wave += (double)(T / E + 6.2383246250395075f - logf(E)); \
        } \
        const float thrM = M - 0.17f; \
        _Pragma("unroll") \
        for (int jj = 0; jj < 8; ++jj) { \
            if (y[jj] > thrM) { \
                const float p_ = __expf((y[jj] - M) * 100.0f); \
                const int k_ = (jj < 4) ? (4*l + jj) : (256 + 4*l + jj - 4); \
                const int idx = atomicAdd(&kcnt[tt], 1); \
                if (idx < 24) { klist[tt][idx] = k_; wlist[tt][idx] = p_; } \
            } \
        } }

    TOKEN(0, A0, A1, { C0 = g4[256 + l]; C1 = g4[320 + l]; })
    TOKEN(1, B0, B1, { A0 = g4[384 + l]; A1 = g4[448 + l]; })
    TOKEN(2, C0, C1, { B0 = g4[512 + l]; B1 = g4[576 + l]; })
    TOKEN(3, A0, A1, { C0 = g4[640 + l]; C1 = g4[704 + l]; })
    TOKEN(4, B0, B1, { A0 = g4[768 + l]; A1 = g4[832 + l]; })
    TOKEN(5, C0, C1, { B0 = g4[896 + l]; B1 = g4[960 + l]; })
    TOKEN(6, A0, A1, {})
    TOKEN(7, B0, B1, {})
#undef TOKEN
#undef KSTEP
#undef BSTEP
#undef SH32

    if (l == 0) kldp[w] = kld_wave;
    __syncthreads();
    if (tid == 0) {
        double acc = 0.0;
        #pragma unroll
        for (int i = 0; i < 8; ++i) acc += kldp[i];
        atomicAdd(&ws[NK], acc);
        __threadfence();
        unsigned* ctr = reinterpret_cast<unsigned*>(ws + NK + 1);
        const unsigned t = atomicAdd(ctr, 1u);
        if (t == 511u) {                        // last block finalizes kld
            __threadfence();
            const double tot = atomicAdd(&ws[NK], 0.0);   // atomic read
            out[OFF_KLD] = (float)(tot * (1.0 / 32768.0));
        }
    }

    // ---- Finalize: per-token S from list, normalize, sparse mat scatter ----
    if (tid < 64) {
        const int cnt = min(kcnt[tid], 24);
        float S = 0.f;
        for (int e = 0; e < cnt; ++e) S += wlist[tid][e];
        const float inv = 1.f / S;              // excluded mass < 2e-5 rel
        float* orow = out + OFF_MAT + ((size_t)b * NK) * NHW + n0 + tid;
        for (int e = 0; e < cnt; ++e) {
            const float wgt = wlist[tid][e] * inv;
            wlist[tid][e] = wgt;
            orow[(size_t)klist[tid][e] * NHW] = wgt;      // scatter on zeroed bg
        }
        kcnt[tid] = cnt;
    }
    __syncthreads();

    // ---- Phase D: sel_codewords from sparse list (NT stores, 256B runs) ----
    {
        const int cnt = kcnt[l];
        #pragma unroll
        for (int half = 0; half < 2; ++half) {
            float acc[16];
            #pragma unroll
            for (int i2 = 0; i2 < 16; ++i2) acc[i2] = 0.f;
            for (int e = 0; e < cnt; ++e) {
                const int k = klist[l][e];
                const float wgt = wlist[l][e];
                const float4* cr = reinterpret_cast<const float4*>(
                    cb + (size_t)k * NC + w * 32 + half * 16);
                #pragma unroll
                for (int q = 0; q < 4; ++q) {
                    const float4 v = cr[q];
                    acc[q * 4 + 0] += wgt * v.x; acc[q * 4 + 1] += wgt * v.y;
                    acc[q * 4 + 2] += wgt * v.z; acc[q * 4 + 3] += wgt * v.w;
                }
            }
            float* basep = out + OFF_SEL + ((size_t)b * NC + w * 32 + half * 16) * NHW + n0 + l;
            #pragma unroll
            for (int i2 = 0; i2 < 16; ++i2)
                __builtin_nontemporal_store(acc[i2], basep + (size_t)i2 * NHW);
        }
    }
}

extern "C" void kernel_launch(void* const* d_in, const int* in_sizes, int n_in,
                              void* d_out, int out_size, void* d_ws, size_t ws_size,
                              hipStream_t stream) {
    const float* feats = (const float*)d_in[0];
    const float* cb    = (const float*)d_in[1];
    const float* gum   = (const float*)d_in[2];
    double* ws = (double*)d_ws;
    float* out = (float*)d_out;
    zprep<<<2048, 256, 0, stream>>>(cb, ws, out);
    gs_main<<<512, 512, 0, stream>>>(feats, gum, cb, ws, out);
}